// Round 2
// baseline (242.642 us; speedup 1.0000x reference)
//
#include <hip/hip_runtime.h>

// ReactDiffDynamics: dUdt = a*lap(U) + U - U^3 - k - V ; dVdt = b*lap(V) + U - V
// Periodic 5-point Laplacian (jnp.roll semantics), B=64, H=W=512, fp32.
// Memory-bound. Ideal traffic 268 MB -> ~43 us @ 6.3 TB/s.
//
// v2b: rolling-register row walk. Each thread owns a fixed float4 column and
// walks ROWS_PER_LANE consecutive rows, carrying north/center rows in regs so
// only the south row is freshly fetched each step. Read amplification drops
// from ~2x (2-row blocks, halo on different XCDs) to (R+2)/R = 1.25x.
// Non-temporal stores keep the never-re-read output out of L2.
// (v2 failed to compile: nontemporal builtin needs a native vector type,
//  not HIP_vector_type<float,4> — use ext_vector_type(4) for the store.)

typedef float v4f __attribute__((ext_vector_type(4)));

constexpr int B = 64;
constexpr int H = 512;
constexpr int W = 512;
constexpr int W4 = W / 4;                          // 128 float4 groups per row
constexpr int PLANE = H * W;
constexpr int ROWS_PER_LANE = 8;                   // rows each thread walks
constexpr int LANES = 2;                           // 256 threads / 128 cols
constexpr int TILE_ROWS = ROWS_PER_LANE * LANES;   // 16 rows per block
constexpr int TILES_PER_B = H / TILE_ROWS;         // 32 tiles per batch image

__global__ __launch_bounds__(256) void react_diff_kernel(
    const float* __restrict__ x,       // (B, 2, H, W)
    const float* __restrict__ params,  // (B, 3)
    float* __restrict__ out)           // (B, 2, H, W)
{
    const float inv_dx2 = 240.25f;     // 1/dx^2, dx = 2/31

    const int wv   = threadIdx.x & (W4 - 1);   // column group [0,128)
    const int lane = threadIdx.x >> 7;         // row-lane 0/1
    const int tile = blockIdx.x;
    const int b    = tile / TILES_PER_B;       // block-uniform batch
    const int trow = tile % TILES_PER_B;
    int h = trow * TILE_ROWS + lane * ROWS_PER_LANE;

    const float* Ub = x + (size_t)b * 2 * PLANE;
    const float* Vb = Ub + PLANE;
    float* oU = out + (size_t)b * 2 * PLANE;
    float* oV = oU + PLANE;

    // block-uniform -> scalar loads
    const float ca = params[b * 3 + 0] * inv_dx2;
    const float cb = params[b * 3 + 1] * inv_dx2;
    const float pk = params[b * 3 + 2];

    const int w0 = wv * 4;
    const int wW = (wv == 0)      ? W - 1 : w0 - 1;  // west wrap
    const int wE = (wv == W4 - 1) ? 0     : w0 + 4;  // east wrap

    // prologue: north (h-1, periodic) and center (h) rows into registers
    const int hn = (h == 0) ? H - 1 : h - 1;
    float4 Un = ((const float4*)(Ub + (size_t)hn * W))[wv];
    float4 Uc = ((const float4*)(Ub + (size_t)h  * W))[wv];
    float4 Vn = ((const float4*)(Vb + (size_t)hn * W))[wv];
    float4 Vc = ((const float4*)(Vb + (size_t)h  * W))[wv];

    #pragma unroll
    for (int r = 0; r < ROWS_PER_LANE; ++r) {
        const int hs = (h == H - 1) ? 0 : h + 1;   // south wrap (only at h=511)
        const size_t rc = (size_t)h  * W;
        const size_t rs = (size_t)hs * W;

        float4 Us = ((const float4*)(Ub + rs))[wv];
        float4 Vs = ((const float4*)(Vb + rs))[wv];
        float  Uw = Ub[rc + wW];   // L1-hit: same lines as neighbors' float4s
        float  Ue = Ub[rc + wE];
        float  Vw = Vb[rc + wW];
        float  Ve = Vb[rc + wE];

        float4 lapU, lapV;
        lapU.x = Un.x + Us.x + Uw   + Uc.y - 4.0f * Uc.x;
        lapU.y = Un.y + Us.y + Uc.x + Uc.z - 4.0f * Uc.y;
        lapU.z = Un.z + Us.z + Uc.y + Uc.w - 4.0f * Uc.z;
        lapU.w = Un.w + Us.w + Uc.z + Ue   - 4.0f * Uc.w;

        lapV.x = Vn.x + Vs.x + Vw   + Vc.y - 4.0f * Vc.x;
        lapV.y = Vn.y + Vs.y + Vc.x + Vc.z - 4.0f * Vc.y;
        lapV.z = Vn.z + Vs.z + Vc.y + Vc.w - 4.0f * Vc.z;
        lapV.w = Vn.w + Vs.w + Vc.z + Ve   - 4.0f * Vc.w;

        v4f dU, dV;
        dU.x = ca * lapU.x + Uc.x - Uc.x * Uc.x * Uc.x - pk - Vc.x;
        dU.y = ca * lapU.y + Uc.y - Uc.y * Uc.y * Uc.y - pk - Vc.y;
        dU.z = ca * lapU.z + Uc.z - Uc.z * Uc.z * Uc.z - pk - Vc.z;
        dU.w = ca * lapU.w + Uc.w - Uc.w * Uc.w * Uc.w - pk - Vc.w;

        dV.x = cb * lapV.x + Uc.x - Vc.x;
        dV.y = cb * lapV.y + Uc.y - Vc.y;
        dV.z = cb * lapV.z + Uc.z - Vc.z;
        dV.w = cb * lapV.w + Uc.w - Vc.w;

        __builtin_nontemporal_store(dU, (v4f*)(oU + rc) + wv);
        __builtin_nontemporal_store(dV, (v4f*)(oV + rc) + wv);

        // roll registers: center -> north, south -> center
        Un = Uc; Uc = Us;
        Vn = Vc; Vc = Vs;
        h = hs;
    }
}

extern "C" void kernel_launch(void* const* d_in, const int* in_sizes, int n_in,
                              void* d_out, int out_size, void* d_ws, size_t ws_size,
                              hipStream_t stream) {
    // d_in[0] = t (1 float, unused), d_in[1] = x (B,2,H,W), d_in[2] = params (B,3)
    const float* x      = (const float*)d_in[1];
    const float* params = (const float*)d_in[2];
    float* out          = (float*)d_out;

    int grid = B * TILES_PER_B;   // 2048 blocks, 256 threads: 8 blocks/CU
    react_diff_kernel<<<grid, 256, 0, stream>>>(x, params, out);
}

// Round 3
// 235.399 us; speedup vs baseline: 1.0308x; 1.0308x over previous
//
#include <hip/hip_runtime.h>

// ReactDiffDynamics: dUdt = a*lap(U) + U - U^3 - k - V ; dVdt = b*lap(V) + U - V
// Periodic 5-point Laplacian (jnp.roll semantics), B=64, H=W=512, fp32.
// Memory-bound. Ideal HBM traffic ~265 MB -> ~42 us @ 6.3 TB/s.
//
// v3: back to v1's one-shot high-turnover structure (16384 blocks, one float4
// column x 2 channels per thread) — v2's serial 8-row walk was latency-bound
// (2048 blocks, vmcnt(0) per iter @ 32 VGPRs: hbm 33%, VALU 6.5%).
// Kept from v2: non-temporal stores (output is never re-read; keeps 131 MB of
// writes from evicting x out of L2/L3 — v2 measured FETCH 84 MB < 128 MB input).
// New: XCD-aware block swizzle — adjacent blocks share halo rows; contiguous
// 2048-block chunks per XCD turn halo re-reads into same-XCD L2 hits.
// params folded: ca = a/dx^2, cb = b/dx^2, b block-uniform -> scalar loads.

typedef float v4f __attribute__((ext_vector_type(4)));

constexpr int B = 64;
constexpr int H = 512;
constexpr int W = 512;
constexpr int W4 = W / 4;            // 128 float4 groups per row
constexpr int PLANE = H * W;
constexpr int GRID = B * H * W4 / 256;   // 16384 blocks
constexpr int CHUNK = GRID / 8;          // blocks per XCD chunk (2048)

__global__ __launch_bounds__(256) void react_diff_kernel(
    const float* __restrict__ x,       // (B, 2, H, W)
    const float* __restrict__ params,  // (B, 3)
    float* __restrict__ out)           // (B, 2, H, W)
{
    const float inv_dx2 = 240.25f;     // 1/dx^2, dx = 2/31

    // XCD swizzle: hw XCD = blockIdx % 8; give each XCD a contiguous chunk
    const int bid = blockIdx.x;
    const int swz = (bid & 7) * CHUNK + (bid >> 3);

    const int tid = swz * 256 + (int)threadIdx.x;  // [0, B*H*W4)
    const int wv  = tid & (W4 - 1);
    const int rem = tid >> 7;          // tid / W4
    const int h   = rem & (H - 1);
    const int b   = rem >> 9;          // rem / H  (block-uniform)

    const int hn = (h == 0)     ? H - 1 : h - 1;   // roll(+1): f[h-1]
    const int hs = (h == H - 1) ? 0     : h + 1;   // roll(-1): f[h+1]
    const int w0 = wv * 4;
    const int wW = (wv == 0)      ? W - 1 : w0 - 1;  // west wrap
    const int wE = (wv == W4 - 1) ? 0     : w0 + 4;  // east wrap

    const float* Ub = x + (size_t)b * 2 * PLANE;
    const float* Vb = Ub + PLANE;

    const size_t rc = (size_t)h  * W;
    const size_t rn = (size_t)hn * W;
    const size_t rs = (size_t)hs * W;

    float4 Uc = ((const float4*)(Ub + rc))[wv];
    float4 Un = ((const float4*)(Ub + rn))[wv];
    float4 Us = ((const float4*)(Ub + rs))[wv];
    float  Uw = Ub[rc + wW];
    float  Ue = Ub[rc + wE];

    float4 Vc = ((const float4*)(Vb + rc))[wv];
    float4 Vn = ((const float4*)(Vb + rn))[wv];
    float4 Vs = ((const float4*)(Vb + rs))[wv];
    float  Vw = Vb[rc + wW];
    float  Ve = Vb[rc + wE];

    // block-uniform -> scalar loads
    const float ca = params[b * 3 + 0] * inv_dx2;
    const float cb = params[b * 3 + 1] * inv_dx2;
    const float pk = params[b * 3 + 2];

    float4 lapU, lapV;
    lapU.x = Un.x + Us.x + Uw   + Uc.y - 4.0f * Uc.x;
    lapU.y = Un.y + Us.y + Uc.x + Uc.z - 4.0f * Uc.y;
    lapU.z = Un.z + Us.z + Uc.y + Uc.w - 4.0f * Uc.z;
    lapU.w = Un.w + Us.w + Uc.z + Ue   - 4.0f * Uc.w;

    lapV.x = Vn.x + Vs.x + Vw   + Vc.y - 4.0f * Vc.x;
    lapV.y = Vn.y + Vs.y + Vc.x + Vc.z - 4.0f * Vc.y;
    lapV.z = Vn.z + Vs.z + Vc.y + Vc.w - 4.0f * Vc.z;
    lapV.w = Vn.w + Vs.w + Vc.z + Ve   - 4.0f * Vc.w;

    v4f dU, dV;
    dU.x = ca * lapU.x + Uc.x - Uc.x * Uc.x * Uc.x - pk - Vc.x;
    dU.y = ca * lapU.y + Uc.y - Uc.y * Uc.y * Uc.y - pk - Vc.y;
    dU.z = ca * lapU.z + Uc.z - Uc.z * Uc.z * Uc.z - pk - Vc.z;
    dU.w = ca * lapU.w + Uc.w - Uc.w * Uc.w * Uc.w - pk - Vc.w;

    dV.x = cb * lapV.x + Uc.x - Vc.x;
    dV.y = cb * lapV.y + Uc.y - Vc.y;
    dV.z = cb * lapV.z + Uc.z - Vc.z;
    dV.w = cb * lapV.w + Uc.w - Vc.w;

    float* ob = out + (size_t)b * 2 * PLANE;
    __builtin_nontemporal_store(dU, (v4f*)(ob + rc) + wv);
    __builtin_nontemporal_store(dV, (v4f*)(ob + PLANE + rc) + wv);
}

extern "C" void kernel_launch(void* const* d_in, const int* in_sizes, int n_in,
                              void* d_out, int out_size, void* d_ws, size_t ws_size,
                              hipStream_t stream) {
    // d_in[0] = t (1 float, unused), d_in[1] = x (B,2,H,W), d_in[2] = params (B,3)
    const float* x      = (const float*)d_in[1];
    const float* params = (const float*)d_in[2];
    float* out          = (float*)d_out;

    react_diff_kernel<<<GRID, 256, 0, stream>>>(x, params, out);
}

// Round 4
// 233.946 us; speedup vs baseline: 1.0372x; 1.0062x over previous
//
#include <hip/hip_runtime.h>

// ReactDiffDynamics: dUdt = a*lap(U) + U - U^3 - k - V ; dVdt = b*lap(V) + U - V
// Periodic 5-point Laplacian (jnp.roll semantics), B=64, H=W=512, fp32.
// Memory-bound in principle (256 MB min traffic -> ~41 us @ 6.3 TB/s), but
// counters show we are vmem-pipeline-bound: HBM 32%, VALU 12%, occ 77%.
//
// v4: one-shot structure (16384 blocks), XCD swizzle, plain float4 stores.
// New: west/east halo via wave shuffle instead of stride-16B dword gathers.
//   lane l's west value = lane l-1's Uc.w  (__shfl_up),
//   lane l's east value = lane l+1's Uc.x  (__shfl_down);
//   only lane 0 / lane 63 load from memory (2-active-lane dword load).
// Cuts per-wave L1 segment traffic ~32% (4 full-width gathers -> 2 two-lane loads).
// (v3 post-mortem: NT stores regressed vs v1's plain stores; reverted.)

typedef float v4f __attribute__((ext_vector_type(4)));

constexpr int B = 64;
constexpr int H = 512;
constexpr int W = 512;
constexpr int W4 = W / 4;            // 128 float4 groups per row
constexpr int PLANE = H * W;
constexpr int GRID = B * H * W4 / 256;   // 16384 blocks
constexpr int CHUNK = GRID / 8;          // blocks per XCD chunk (2048)

__global__ __launch_bounds__(256) void react_diff_kernel(
    const float* __restrict__ x,       // (B, 2, H, W)
    const float* __restrict__ params,  // (B, 3)
    float* __restrict__ out)           // (B, 2, H, W)
{
    const float inv_dx2 = 240.25f;     // 1/dx^2, dx = 2/31

    // XCD swizzle: hw XCD = blockIdx % 8; give each XCD a contiguous chunk
    const int bid = blockIdx.x;
    const int swz = (bid & 7) * CHUNK + (bid >> 3);

    const int tid  = swz * 256 + (int)threadIdx.x;  // [0, B*H*W4)
    const int lane = threadIdx.x & 63;
    const int wv   = tid & (W4 - 1);
    const int rem  = tid >> 7;          // tid / W4
    const int h    = rem & (H - 1);
    const int b    = rem >> 9;          // rem / H  (block-uniform)

    const int hn = (h == 0)     ? H - 1 : h - 1;   // roll(+1): f[h-1]
    const int hs = (h == H - 1) ? 0     : h + 1;   // roll(-1): f[h+1]
    const int w0 = wv * 4;
    const int wW = (wv == 0)      ? W - 1 : w0 - 1;  // west wrap
    const int wE = (wv == W4 - 1) ? 0     : w0 + 4;  // east wrap

    const float* Ub = x + (size_t)b * 2 * PLANE;
    const float* Vb = Ub + PLANE;

    const size_t rc = (size_t)h  * W;
    const size_t rn = (size_t)hn * W;
    const size_t rs = (size_t)hs * W;

    float4 Uc = ((const float4*)(Ub + rc))[wv];
    float4 Un = ((const float4*)(Ub + rn))[wv];
    float4 Us = ((const float4*)(Ub + rs))[wv];
    float4 Vc = ((const float4*)(Vb + rc))[wv];
    float4 Vn = ((const float4*)(Vb + rn))[wv];
    float4 Vs = ((const float4*)(Vb + rs))[wv];

    // W/E halo from neighbor lanes' registers
    float Uw = __shfl_up(Uc.w, 1);     // lane l-1's element w0-1
    float Vw = __shfl_up(Vc.w, 1);
    float Ue = __shfl_down(Uc.x, 1);   // lane l+1's element w0+4
    float Ve = __shfl_down(Vc.x, 1);
    if (lane == 0 || lane == 63) {
        const int off = (lane == 0) ? wW : wE;   // per-lane border column
        const float ub = Ub[rc + off];
        const float vb = Vb[rc + off];
        if (lane == 0) { Uw = ub; Vw = vb; }
        else           { Ue = ub; Ve = vb; }
    }

    // block-uniform -> scalar loads
    const float ca = params[b * 3 + 0] * inv_dx2;
    const float cb = params[b * 3 + 1] * inv_dx2;
    const float pk = params[b * 3 + 2];

    float4 lapU, lapV;
    lapU.x = Un.x + Us.x + Uw   + Uc.y - 4.0f * Uc.x;
    lapU.y = Un.y + Us.y + Uc.x + Uc.z - 4.0f * Uc.y;
    lapU.z = Un.z + Us.z + Uc.y + Uc.w - 4.0f * Uc.z;
    lapU.w = Un.w + Us.w + Uc.z + Ue   - 4.0f * Uc.w;

    lapV.x = Vn.x + Vs.x + Vw   + Vc.y - 4.0f * Vc.x;
    lapV.y = Vn.y + Vs.y + Vc.x + Vc.z - 4.0f * Vc.y;
    lapV.z = Vn.z + Vs.z + Vc.y + Vc.w - 4.0f * Vc.z;
    lapV.w = Vn.w + Vs.w + Vc.z + Ve   - 4.0f * Vc.w;

    float4 dU, dV;
    dU.x = ca * lapU.x + Uc.x - Uc.x * Uc.x * Uc.x - pk - Vc.x;
    dU.y = ca * lapU.y + Uc.y - Uc.y * Uc.y * Uc.y - pk - Vc.y;
    dU.z = ca * lapU.z + Uc.z - Uc.z * Uc.z * Uc.z - pk - Vc.z;
    dU.w = ca * lapU.w + Uc.w - Uc.w * Uc.w * Uc.w - pk - Vc.w;

    dV.x = cb * lapV.x + Uc.x - Vc.x;
    dV.y = cb * lapV.y + Uc.y - Vc.y;
    dV.z = cb * lapV.z + Uc.z - Vc.z;
    dV.w = cb * lapV.w + Uc.w - Vc.w;

    float* ob = out + (size_t)b * 2 * PLANE;
    ((float4*)(ob + rc))[wv]         = dU;
    ((float4*)(ob + PLANE + rc))[wv] = dV;
}

extern "C" void kernel_launch(void* const* d_in, const int* in_sizes, int n_in,
                              void* d_out, int out_size, void* d_ws, size_t ws_size,
                              hipStream_t stream) {
    // d_in[0] = t (1 float, unused), d_in[1] = x (B,2,H,W), d_in[2] = params (B,3)
    const float* x      = (const float*)d_in[1];
    const float* params = (const float*)d_in[2];
    float* out          = (float*)d_out;

    react_diff_kernel<<<GRID, 256, 0, stream>>>(x, params, out);
}